// Round 4
// baseline (251.920 us; speedup 1.0000x reference)
//
#include <hip/hip_runtime.h>
#include <math.h>

typedef _Float16 h16;
typedef _Float16 half8 __attribute__((ext_vector_type(8)));
typedef float f32x4 __attribute__((ext_vector_type(4)));

#define NB 2
#define NS 2047
#define NC 1024
#define NN 2048
#define NH 16
#define ND 64

__device__ __forceinline__ void gl_lds16(const h16* g, h16* l) {
  __builtin_amdgcn_global_load_lds((const __attribute__((address_space(1))) void*)g,
                                   (__attribute__((address_space(3))) void*)l, 16, 0, 0);
}
__device__ __forceinline__ f32x4 mfma16(half8 a, half8 b, f32x4 c) {
  return __builtin_amdgcn_mfma_f32_16x16x32_f16(a, b, c, 0, 0, 0);
}

// ---------- cast x (+global token concat) to f16: xgh[b][n][c] ----------
__global__ __launch_bounds__(256) void cast_xg_k(
    const float* __restrict__ x, const float* __restrict__ g, h16* __restrict__ out) {
  size_t i = ((size_t)blockIdx.x * 256 + threadIdx.x) * 16;
  const int c = (int)(i & (NC - 1));
  const int n = (int)((i >> 10) & (NN - 1));
  const int b = (int)(i >> 21);
  const float* src = (n == 0) ? (g + c) : (x + ((size_t)b * NS + (n - 1)) * NC + c);
  h16 tmp[16];
#pragma unroll
  for (int j = 0; j < 4; ++j) {
    float4 f = ((const float4*)src)[j];
    tmp[4 * j + 0] = (h16)f.x; tmp[4 * j + 1] = (h16)f.y;
    tmp[4 * j + 2] = (h16)f.z; tmp[4 * j + 3] = (h16)f.w;
  }
  *(half8*)(out + i) = *(half8*)&tmp[0];
  *(half8*)(out + i + 8) = *(half8*)&tmp[8];
}

// ---------- both weight casts in one kernel (w3h|wph contiguous) ----------
__global__ __launch_bounds__(256) void cast_w_k(
    const float* __restrict__ qw, const float* __restrict__ pw, h16* __restrict__ out) {
  size_t i = ((size_t)blockIdx.x * 256 + threadIdx.x) * 8;
  const float* src = (i < (size_t)3 * NC * NC) ? (qw + i) : (pw + (i - (size_t)3 * NC * NC));
  float4 f0 = ((const float4*)src)[0];
  float4 f1 = ((const float4*)src)[1];
  h16 tmp[8];
  tmp[0] = (h16)f0.x; tmp[1] = (h16)f0.y; tmp[2] = (h16)f0.z; tmp[3] = (h16)f0.w;
  tmp[4] = (h16)f1.x; tmp[5] = (h16)f1.y; tmp[6] = (h16)f1.z; tmp[7] = (h16)f1.w;
  *(half8*)(out + i) = *(half8*)&tmp[0];
}

// ---------- QKV GEMM (MFMA f16, global_load_lds staging) ----------
__global__ __launch_bounds__(256) void gemm_qkv_h(
    const h16* __restrict__ A, const h16* __restrict__ W, h16* __restrict__ out) {
  __shared__ h16 As[128 * 32];
  __shared__ h16 Bs[128 * 32];
  const int tid = threadIdx.x;
  const int m0 = blockIdx.y * 128, j0 = blockIdx.x * 128;
  const int wid = tid >> 6, lane = tid & 63, l15 = lane & 15, quad = lane >> 4;
  const h16* ag = A + (size_t)(m0 + wid * 32 + (lane >> 2)) * NC + (lane & 3) * 8;
  const h16* bg = W + (size_t)(j0 + wid * 32 + (lane >> 2)) * NC + (lane & 3) * 8;
  h16* lA = &As[wid * 32 * 32];
  h16* lB = &Bs[wid * 32 * 32];
  f32x4 acc[2][8];
#pragma unroll
  for (int rt = 0; rt < 2; ++rt)
#pragma unroll
    for (int ct = 0; ct < 8; ++ct) acc[rt][ct] = (f32x4){0.f, 0.f, 0.f, 0.f};

  for (int k0 = 0; k0 < NC; k0 += 32) {
    __syncthreads();
    gl_lds16(ag + k0, lA);
    gl_lds16(ag + k0 + 16 * NC, lA + 16 * 32);
    gl_lds16(bg + k0, lB);
    gl_lds16(bg + k0 + 16 * NC, lB + 16 * 32);
    __syncthreads();
    half8 af0 = *(const half8*)&As[(wid * 32 + l15) * 32 + quad * 8];
    half8 af1 = *(const half8*)&As[(wid * 32 + 16 + l15) * 32 + quad * 8];
#pragma unroll
    for (int ct = 0; ct < 8; ++ct) {
      half8 bf = *(const half8*)&Bs[(ct * 16 + l15) * 32 + quad * 8];
      acc[0][ct] = mfma16(af0, bf, acc[0][ct]);
      acc[1][ct] = mfma16(af1, bf, acc[1][ct]);
    }
  }
#pragma unroll
  for (int rt = 0; rt < 2; ++rt)
#pragma unroll
    for (int ct = 0; ct < 8; ++ct)
#pragma unroll
      for (int r = 0; r < 4; ++r) {
        const int mm = m0 + wid * 32 + rt * 16 + quad * 4 + r;
        const int jj = j0 + ct * 16 + l15;
        out[(size_t)mm * (3 * NC) + jj] = (h16)acc[rt][ct][r];
      }
}

// ---------- V transpose: vT[b][h][d][n] from qkvh ----------
__global__ __launch_bounds__(256) void vtrans_k(
    const h16* __restrict__ qkvh, h16* __restrict__ vT) {
  __shared__ h16 ts[64 * 72];
  const int kb = blockIdx.x, h = blockIdx.y, b = blockIdx.z;
  const int t = threadIdx.x;
  const int key = t >> 2, co = (t & 3) * 16;
  const h16* src = qkvh + (size_t)(b * NN + kb * 64 + key) * (3 * NC) + 2 * NC + h * ND + co;
  half8 v0 = *(const half8*)src;
  half8 v1 = *(const half8*)(src + 8);
  *(half8*)&ts[key * 72 + co] = v0;
  *(half8*)&ts[key * 72 + co + 8] = v1;
  __syncthreads();
  const int d = t >> 2, ko = (t & 3) * 16;
  h16 buf[16];
#pragma unroll
  for (int i = 0; i < 16; ++i) buf[i] = ts[(ko + i) * 72 + d];
  h16* dst = vT + ((size_t)(b * NH + h) * ND + d) * NN + kb * 64 + ko;
  *(half8*)dst = *(half8*)&buf[0];
  *(half8*)(dst + 8) = *(half8*)&buf[8];
}

// ---------- MFMA flash attention: paired q-blocks, parity key-split ----------
__device__ __forceinline__ void attn_tile(
    half8 aq0, half8 aq1, const h16* Ks, const h16* Vs, h16* Pw,
    int l15, int quad, f32x4* o, float* den) {
  f32x4 s[4];
#pragma unroll
  for (int ct = 0; ct < 4; ++ct) {
    half8 bk0 = *(const half8*)&Ks[(ct * 16 + l15) * 72 + quad * 8];
    half8 bk1 = *(const half8*)&Ks[(ct * 16 + l15) * 72 + 32 + quad * 8];
    f32x4 z = (f32x4){0.f, 0.f, 0.f, 0.f};
    z = mfma16(aq0, bk0, z);
    s[ct] = mfma16(aq1, bk1, z);
  }
#pragma unroll
  for (int ct = 0; ct < 4; ++ct)
#pragma unroll
    for (int r = 0; r < 4; ++r) {
      float p = __expf(s[ct][r] * 0.125f);
      den[r] += p;
      Pw[(quad * 4 + r) * 72 + ct * 16 + l15] = (h16)p;
    }
  half8 ap0 = *(const half8*)&Pw[l15 * 72 + quad * 8];
  half8 ap1 = *(const half8*)&Pw[l15 * 72 + 32 + quad * 8];
#pragma unroll
  for (int ct = 0; ct < 4; ++ct) {
    half8 bv0 = *(const half8*)&Vs[(ct * 16 + l15) * 72 + quad * 8];
    half8 bv1 = *(const half8*)&Vs[(ct * 16 + l15) * 72 + 32 + quad * 8];
    o[ct] = mfma16(ap0, bv0, o[ct]);
    o[ct] = mfma16(ap1, bv1, o[ct]);
  }
}

__global__ __launch_bounds__(256, 4) void attn_h(
    const h16* __restrict__ qkvh, const h16* __restrict__ vT,
    h16* __restrict__ Op0, h16* __restrict__ Op1, float* __restrict__ denp) {
  __shared__ h16 Ks[64 * 72];
  __shared__ h16 Vs[64 * 72];
  __shared__ h16 Ps[64 * 72];
  const int pr = blockIdx.x & 15;   // pair index: q1=pr, q2=31-pr
  const int c = blockIdx.x >> 4;    // parity chunk 0/1
  const int q1 = pr, q2 = 31 - pr;
  const int h = blockIdx.y, b = blockIdx.z;
  const int tid = threadIdx.x, wid = tid >> 6, lane = tid & 63;
  const int l15 = lane & 15, quad = lane >> 4;
  const h16* q1src = qkvh + (size_t)(b * NN + q1 * 64 + wid * 16 + l15) * (3 * NC) + h * ND + quad * 8;
  const h16* q2src = qkvh + (size_t)(b * NN + q2 * 64 + wid * 16 + l15) * (3 * NC) + h * ND + quad * 8;
  half8 a1q0 = *(const half8*)q1src;
  half8 a1q1 = *(const half8*)(q1src + 32);
  half8 a2q0 = *(const half8*)q2src;
  half8 a2q1 = *(const half8*)(q2src + 32);
  f32x4 o1[4], o2[4];
  float d1[4] = {0.f, 0.f, 0.f, 0.f}, d2[4] = {0.f, 0.f, 0.f, 0.f};
#pragma unroll
  for (int ct = 0; ct < 4; ++ct) {
    o1[ct] = (f32x4){0.f, 0.f, 0.f, 0.f};
    o2[ct] = (f32x4){0.f, 0.f, 0.f, 0.f};
  }
  const int skey = tid >> 2, sco = (tid & 3) * 16;
  const h16* kbase = qkvh + (size_t)(b * NN + skey) * (3 * NC) + NC + h * ND + sco;
  const h16* vbase = vT + ((size_t)(b * NH + h) * ND + skey) * NN + sco;
  h16* Pw = &Ps[(wid * 16) * 72];

  // prefetch first K/V block of this parity chunk
  int kb = c;
  const h16* kp = kbase + (size_t)kb * (64 * 3 * NC);
  const h16* vp = vbase + kb * 64;
  half8 k0 = *(const half8*)kp, k1 = *(const half8*)(kp + 8);
  half8 v0 = *(const half8*)vp, v1 = *(const half8*)(vp + 8);

  for (; kb <= q2; kb += 2) {
    __syncthreads();
    *(half8*)&Ks[skey * 72 + sco] = k0; *(half8*)&Ks[skey * 72 + sco + 8] = k1;
    *(half8*)&Vs[skey * 72 + sco] = v0; *(half8*)&Vs[skey * 72 + sco + 8] = v1;
    __syncthreads();
    const int nkb = (kb + 2 <= q2) ? (kb + 2) : kb;  // clamp: harmless re-read
    kp = kbase + (size_t)nkb * (64 * 3 * NC);
    vp = vbase + nkb * 64;
    k0 = *(const half8*)kp; k1 = *(const half8*)(kp + 8);
    v0 = *(const half8*)vp; v1 = *(const half8*)(vp + 8);
    attn_tile(a2q0, a2q1, Ks, Vs, Pw, l15, quad, o2, d2);
    if (kb <= q1) attn_tile(a1q0, a1q1, Ks, Vs, Pw, l15, quad, o1, d1);
  }
#pragma unroll
  for (int r = 0; r < 4; ++r)
#pragma unroll
    for (int off = 1; off < 16; off <<= 1) {
      d1[r] += __shfl_xor(d1[r], off);
      d2[r] += __shfl_xor(d2[r], off);
    }
  h16* op = (c == 0) ? Op0 : Op1;
  const size_t rbase = (size_t)(b * NH + h) * NN;
  float* dch = denp + (size_t)c * (NB * NH * NN);
#pragma unroll
  for (int ct = 0; ct < 4; ++ct)
#pragma unroll
    for (int r = 0; r < 4; ++r) {
      const int n1 = q1 * 64 + wid * 16 + quad * 4 + r;
      const int n2 = q2 * 64 + wid * 16 + quad * 4 + r;
      op[(rbase + n1) * ND + ct * 16 + l15] = (h16)o1[ct][r];
      op[(rbase + n2) * ND + ct * 16 + l15] = (h16)o2[ct][r];
      if (ct == 0 && l15 == 0) {
        dch[rbase + n1] = d1[r];
        dch[rbase + n2] = d2[r];
      }
    }
}

// ---------- merge partials: attnh = (O0+O1)/(d0+d1) ----------
__global__ __launch_bounds__(256) void merge_k(
    const h16* __restrict__ Op0, const h16* __restrict__ Op1,
    const float* __restrict__ denp, h16* __restrict__ attnh) {
  const size_t t = (size_t)blockIdx.x * 256 + threadIdx.x;  // 524288 threads
  const int d = (int)(t & 7) * 8;
  const size_t row = t >> 3;  // (b*NH+h)*NN + n
  half8 a = *(const half8*)(Op0 + row * ND + d);
  half8 bb8 = *(const half8*)(Op1 + row * ND + d);
  const float inv = 1.f / (denp[row] + denp[(size_t)NB * NH * NN + row]);
  h16 o[8];
#pragma unroll
  for (int j = 0; j < 8; ++j) o[j] = (h16)(((float)a[j] + (float)bb8[j]) * inv);
  const int n = (int)(row & (NN - 1));
  const int h = (int)((row >> 11) & (NH - 1));
  const int b = (int)(row >> 15);
  *(half8*)(attnh + (size_t)(b * NN + n) * NC + h * ND + d) = *(half8*)&o[0];
}

// ---------- proj GEMM (MFMA f16) + bias, fp32 out. 64x128 tile ----------
__global__ __launch_bounds__(256) void gemm_proj_h(
    const h16* __restrict__ Ah, const h16* __restrict__ W,
    const float* __restrict__ bias, float* __restrict__ out) {
  __shared__ h16 As[64 * 32];
  __shared__ h16 Bs[128 * 32];
  const int tid = threadIdx.x;
  const int m0 = blockIdx.y * 64, j0 = blockIdx.x * 128;
  const int wid = tid >> 6, lane = tid & 63, l15 = lane & 15, quad = lane >> 4;
  int m = m0 + wid * 16 + (lane >> 2);
  if (m > NB * NS - 1) m = NB * NS - 1;
  const int bb = (m >= NS) ? 1 : 0;
  const h16* ag = Ah + (size_t)(bb * NN + m - bb * NS + 1) * NC + (lane & 3) * 8;
  const h16* bg = W + (size_t)(j0 + wid * 32 + (lane >> 2)) * NC + (lane & 3) * 8;
  h16* lA = &As[wid * 16 * 32];
  h16* lB = &Bs[wid * 32 * 32];
  f32x4 acc[8];
#pragma unroll
  for (int ct = 0; ct < 8; ++ct) acc[ct] = (f32x4){0.f, 0.f, 0.f, 0.f};

  for (int k0 = 0; k0 < NC; k0 += 32) {
    __syncthreads();
    gl_lds16(ag + k0, lA);
    gl_lds16(bg + k0, lB);
    gl_lds16(bg + k0 + 16 * NC, lB + 16 * 32);
    __syncthreads();
    half8 af = *(const half8*)&As[(wid * 16 + l15) * 32 + quad * 8];
#pragma unroll
    for (int ct = 0; ct < 8; ++ct) {
      half8 bf = *(const half8*)&Bs[(ct * 16 + l15) * 32 + quad * 8];
      acc[ct] = mfma16(af, bf, acc[ct]);
    }
  }
#pragma unroll
  for (int ct = 0; ct < 8; ++ct) {
    const float bv = bias[j0 + ct * 16 + l15];
#pragma unroll
    for (int r = 0; r < 4; ++r) {
      const int mm = m0 + wid * 16 + quad * 4 + r;
      if (mm < NB * NS)
        out[(size_t)mm * NC + j0 + ct * 16 + l15] = acc[ct][r] + bv;
    }
  }
}

extern "C" void kernel_launch(void* const* d_in, const int* in_sizes, int n_in,
                              void* d_out, int out_size, void* d_ws, size_t ws_size,
                              hipStream_t stream) {
  const float* x = (const float*)d_in[0];
  const float* g = (const float*)d_in[1];
  const float* qkv_w = (const float*)d_in[2];
  const float* proj_w = (const float*)d_in[3];
  const float* proj_b = (const float*)d_in[4];
  float* out = (float*)d_out;

  h16* xgh  = (h16*)d_ws;                        // 4.19M h16; reused as Op0 after gemm_qkv
  h16* w3h  = xgh + (size_t)NB * NN * NC;        // 3.15M h16
  h16* wph  = w3h + (size_t)3 * NC * NC;         // 1.05M h16
  h16* qkvh = wph + (size_t)NC * NC;             // 12.6M h16
  h16* vTh  = qkvh + (size_t)NB * NN * 3 * NC;   // 2.10M h16
  h16* attnh = vTh + (size_t)NB * NH * ND * NN;  // 4.19M h16
  h16* op1  = attnh + (size_t)NB * NN * NC;      // 4.19M h16
  float* den = (float*)(op1 + (size_t)NB * NN * NC);  // 2*65536 f32
  h16* op0 = xgh;

  cast_xg_k<<<dim3(1024), 256, 0, stream>>>(x, g, xgh);
  cast_w_k<<<dim3(2048), 256, 0, stream>>>(qkv_w, proj_w, w3h);
  gemm_qkv_h<<<dim3(24, 32), 256, 0, stream>>>(xgh, w3h, qkvh);
  vtrans_k<<<dim3(32, NH, NB), 256, 0, stream>>>(qkvh, vTh);
  attn_h<<<dim3(32, NH, NB), 256, 0, stream>>>(qkvh, vTh, op0, op1, den);
  merge_k<<<dim3(2048), 256, 0, stream>>>(op0, op1, den, attnh);
  gemm_proj_h<<<dim3(8, 64), 256, 0, stream>>>(attnh, wph, proj_b, out);
}